// Round 5
// baseline (196.098 us; speedup 1.0000x reference)
//
#include <hip/hip_runtime.h>

// Problem constants (from setup_inputs)
#define V_    50000
#define D_    128
#define HOPS_ 3
#define B_    16
#define LC_   256
#define MC_   8
#define LK_   512
#define MK_   8

typedef __bf16  bf16x8  __attribute__((ext_vector_type(8)));
typedef unsigned short ushort8 __attribute__((ext_vector_type(8)));
typedef unsigned short ushort4v __attribute__((ext_vector_type(4)));
typedef float   floatx4 __attribute__((ext_vector_type(4)));

__device__ inline unsigned short f2bf(float f) {
    union { float f; unsigned u; } x; x.f = f;
    unsigned r = x.u + 0x7FFFu + ((x.u >> 16) & 1u);   // RNE
    return (unsigned short)(r >> 16);
}

__device__ inline floatx4 mfma_bf16(ushort8 a, ushort8 b, floatx4 c) {
    return __builtin_amdgcn_mfma_f32_16x16x32_bf16(
        __builtin_bit_cast(bf16x8, a), __builtin_bit_cast(bf16x8, b), c, 0, 0, 0);
}

// ---------------------------------------------------------------------------
// Kernel 1: embedding-bag gathers. No LDS; 7 blocks/CU. Near DRAM-random floor
// (~151 MB compulsory 512B-row traffic) — R3/R4 both neutral, don't touch.
//   blocks [0,768):    kf tiles (hop,b,ktile of 32 rows)
//   blocks [768,1152): cf tiles (hop,b,ltile of 32 rows)
// ---------------------------------------------------------------------------
__global__ __launch_bounds__(256, 7) void gather_kernel(
    const int* __restrict__ conv_seqs, const int* __restrict__ kb_arr,
    const float* __restrict__ Ct, const float* __restrict__ Kt,
    unsigned short* __restrict__ kf, unsigned short* __restrict__ cf)
{
    const int tid  = threadIdx.x;
    const int r    = tid >> 3;               // row in tile (0..31)
    const int s    = tid & 7;                // position within 8-lane cluster
    const int lane = tid & 63;
    const int bx   = blockIdx.x;

    constexpr int KBLK = HOPS_ * B_ * (LK_ / 32);   // 768

    const int*   idxp;
    const float* table;
    unsigned short* dst;                     // row base (element 0)

    if (bx < KBLK) {
        int hop  = bx / (B_ * 16);
        int rem  = bx % (B_ * 16);
        int b    = rem >> 4;
        int row0 = (rem & 15) * 32;
        idxp  = kb_arr + (size_t)(b * LK_ + row0 + r) * MK_;
        table = Kt + (size_t)hop * V_ * D_;
        dst   = kf + (((size_t)(hop * B_ + b) * LK_) + row0 + r) * D_;
    } else {
        int id   = bx - KBLK;
        int hop  = id / (B_ * 8);
        int rem  = id % (B_ * 8);
        int b    = rem >> 3;
        int row0 = (rem & 7) * 32;
        idxp  = conv_seqs + (size_t)(b * LC_ + row0 + r) * MC_;
        table = Ct + (size_t)hop * V_ * D_;
        dst   = cf + (((size_t)(hop * B_ + b) * LC_) + row0 + r) * D_;
    }

    const int myidx = idxp[s];               // one idx per lane, coalesced
    int idxs[8];
    #pragma unroll
    for (int m = 0; m < 8; ++m)
        idxs[m] = __shfl(myidx, (lane & 56) + m);

    float4 acc[4];
    #pragma unroll
    for (int j = 0; j < 4; ++j) acc[j] = make_float4(0.f, 0.f, 0.f, 0.f);

    #pragma unroll
    for (int m = 0; m < 8; ++m) {
        const float* rowp = table + (size_t)idxs[m] * D_;
        #pragma unroll
        for (int j = 0; j < 4; ++j) {
            float4 v = *(const float4*)(rowp + j * 32 + s * 4);
            acc[j].x += v.x; acc[j].y += v.y; acc[j].z += v.z; acc[j].w += v.w;
        }
    }

    #pragma unroll
    for (int j = 0; j < 4; ++j) {
        ushort4v o;
        o[0] = f2bf(acc[j].x); o[1] = f2bf(acc[j].y);
        o[2] = f2bf(acc[j].z); o[3] = f2bf(acc[j].w);
        *(ushort4v*)(dst + j * 32 + s * 4) = o;
    }
}

// ---------------------------------------------------------------------------
// Kernel 1b: kf -> kfT transpose (64x64 bf16 tiles). 768 blocks.
// ---------------------------------------------------------------------------
__global__ __launch_bounds__(256) void transpose_kernel(
    const unsigned short* __restrict__ kf, unsigned short* __restrict__ kfT)
{
    __shared__ unsigned short tile[64][72];  // stride 144B: 16B-aligned rows

    const int tid = threadIdx.x;
    const int bx  = blockIdx.x;

    const int g  = bx >> 4;                  // 0..47 = hop*16+b
    const int dt = (bx & 15) >> 3;           // 0..1
    const int kt = bx & 7;                   // 0..7
    const int k0 = kt * 64, d0 = dt * 64;

    const int r = tid >> 2;                  // 0..63
    const int c = tid & 3;                   // 0..3

    const unsigned short* src = kf + ((size_t)g * 512 + k0 + r) * 128 + d0 + c * 16;
    ushort8 a = *(const ushort8*)(src);
    ushort8 b = *(const ushort8*)(src + 8);
    *(ushort8*)&tile[r][c * 16]     = a;
    *(ushort8*)&tile[r][c * 16 + 8] = b;
    __syncthreads();

    unsigned short* dstp = kfT + ((size_t)g * 128 + d0 + r) * 512 + k0 + c * 16;
    ushort8 o0, o1;
    #pragma unroll
    for (int i = 0; i < 8; ++i) o0[i] = tile[c * 16 + i][r];
    #pragma unroll
    for (int i = 0; i < 8; ++i) o1[i] = tile[c * 16 + 8 + i][r];
    *(ushort8*)(dstp)     = o0;
    *(ushort8*)(dstp + 8) = o1;
}

// ---------------------------------------------------------------------------
// Kernel 2: attention, hop-parallel, XCD-swizzled, NO ATOMICS: per-hop
// partials go to part[hop][Lc][B][D] with plain coalesced stores; reduce
// kernel sums hops. 768 blocks x 512 thr.
// ---------------------------------------------------------------------------
__global__ __launch_bounds__(512) void attn_kernel(
    const unsigned short* __restrict__ kf, const unsigned short* __restrict__ kfT,
    const unsigned short* __restrict__ cf, float* __restrict__ part)
{
    constexpr int AS = 516;                  // row stride: %4==0 (b128 align), %32==4 (bank spread)
    __shared__ float att_s[16][AS];          // 33 KB
    __shared__ float rowinv_s[16];

    const int tid  = threadIdx.x;
    const int wave = tid >> 6;               // 0..7
    const int lane = tid & 63;
    const int quad = lane >> 4;              // 0..3
    const int l16  = lane & 15;

    // XCD-swizzle decode
    const int gl  = blockIdx.x & 7;
    const int s_  = blockIdx.x >> 3;         // 0..95
    const int lt  = s_ / 6;                  // 0..15
    const int gh  = s_ % 6;                  // 0..5
    const int g   = gh * 8 + gl;             // 0..47 = hop*16+b
    const int hop = g >> 4;
    const int b   = g & 15;
    const int l0  = lt * 16;

    const unsigned short* cf_h  = cf  + (((size_t)g) * 256 + l0) * 128;
    const unsigned short* kf_h  = kf  + ((size_t)g) * 512 * 128;
    const unsigned short* kfT_h = kfT + ((size_t)g) * 128 * 512;

    // A-fragments (cf rows), reused across all 32 n-tiles
    ushort8 afrag[4];
    #pragma unroll
    for (int ks = 0; ks < 4; ++ks)
        afrag[ks] = *(const ushort8*)(cf_h + l16 * 128 + ks * 32 + quad * 8);

    // -------- Phase A: att = cf @ kf^T --------
    #pragma unroll
    for (int t = 0; t < 4; ++t) {
        const int nt = wave * 4 + t;         // 8 waves x 4 = 32 n-tiles (512 k)
        floatx4 acc = {0.f, 0.f, 0.f, 0.f};
        #pragma unroll
        for (int ks = 0; ks < 4; ++ks) {
            ushort8 bfrag = *(const ushort8*)(kf_h + (nt * 16 + l16) * 128 + ks * 32 + quad * 8);
            acc = mfma_bf16(afrag[ks], bfrag, acc);
        }
        #pragma unroll
        for (int rr = 0; rr < 4; ++rr)
            att_s[quad * 4 + rr][nt * 16 + l16] = acc[rr];
    }
    __syncthreads();

    // -------- softmax: wave handles rows 2*wave, 2*wave+1 --------
    #pragma unroll
    for (int rr = 0; rr < 2; ++rr) {
        const int row = wave * 2 + rr;
        float v[8];
        float mx = -1e30f;
        #pragma unroll
        for (int j = 0; j < 8; ++j) {
            v[j] = att_s[row][lane + j * 64];
            mx = fmaxf(mx, v[j]);
        }
        #pragma unroll
        for (int off = 32; off; off >>= 1) mx = fmaxf(mx, __shfl_xor(mx, off));
        float sum = 0.f;
        #pragma unroll
        for (int j = 0; j < 8; ++j) {
            float e = __expf(v[j] - mx);
            att_s[row][lane + j * 64] = e;
            sum += e;
        }
        #pragma unroll
        for (int off = 32; off; off >>= 1) sum += __shfl_xor(sum, off);
        if (lane == 0) rowinv_s[row] = 1.0f / sum;
    }
    __syncthreads();

    // -------- Phase B: out_tile = p @ kf  (wave owns d-tile = wave) --------
    floatx4 pacc = {0.f, 0.f, 0.f, 0.f};
    #pragma unroll
    for (int ks = 0; ks < 16; ++ks) {
        const float* prow = &att_s[l16][ks * 32 + quad * 8];
        float4 p0 = *(const float4*)(prow);
        float4 p1 = *(const float4*)(prow + 4);
        ushort8 pa;
        pa[0] = f2bf(p0.x); pa[1] = f2bf(p0.y); pa[2] = f2bf(p0.z); pa[3] = f2bf(p0.w);
        pa[4] = f2bf(p1.x); pa[5] = f2bf(p1.y); pa[6] = f2bf(p1.z); pa[7] = f2bf(p1.w);
        ushort8 bfrag = *(const ushort8*)(kfT_h + (size_t)(wave * 16 + l16) * 512 + ks * 32 + quad * 8);
        pacc = mfma_bf16(pa, bfrag, pacc);
    }

    // plain stores to per-hop partial: part[hop][Lc][B][D]
    const int d = wave * 16 + l16;
    float* pbase = part + (size_t)hop * LC_ * B_ * D_;
    #pragma unroll
    for (int rr = 0; rr < 4; ++rr)
        pbase[(((size_t)(l0 + quad * 4 + rr)) * 16 + b) * 128 + d] =
            pacc[rr] * rowinv_s[quad * 4 + rr];
}

// ---------------------------------------------------------------------------
// Kernel 3: reduce 3 hop-partials into d_out. 512 blocks x 256 thr x float4.
// ---------------------------------------------------------------------------
__global__ __launch_bounds__(256) void reduce_kernel(
    const float4* __restrict__ part, float4* __restrict__ out4)
{
    constexpr size_t N4 = (size_t)LC_ * B_ * D_ / 4;   // 131072
    const size_t i = (size_t)blockIdx.x * 256 + threadIdx.x;
    float4 a = part[i], b = part[i + N4], c = part[i + 2 * N4];
    out4[i] = make_float4(a.x + b.x + c.x, a.y + b.y + c.y,
                          a.z + b.z + c.z, a.w + b.w + c.w);
}

extern "C" void kernel_launch(void* const* d_in, const int* in_sizes, int n_in,
                              void* d_out, int out_size, void* d_ws, size_t ws_size,
                              hipStream_t stream) {
    (void)in_sizes; (void)n_in; (void)out_size; (void)ws_size;
    const int*   conv_seqs = (const int*)d_in[0];
    const int*   kb_arr    = (const int*)d_in[1];
    const float* C         = (const float*)d_in[2];
    const float* K         = (const float*)d_in[3];

    // ws layout: kf bf16 [3][16][512][128], kfT bf16 [3][16][128][512],
    //            cf bf16 [3][16][256][128], part fp32 [3][256][16][128]
    unsigned short* kf  = (unsigned short*)d_ws;
    unsigned short* kfT = kf  + (size_t)HOPS_ * B_ * LK_ * D_;
    unsigned short* cf  = kfT + (size_t)HOPS_ * B_ * LK_ * D_;
    float*          part = (float*)(cf + (size_t)HOPS_ * B_ * LC_ * D_);
    float* out = (float*)d_out;

    hipLaunchKernelGGL(gather_kernel, dim3(1152), dim3(256), 0, stream,
                       conv_seqs, kb_arr, C, K, kf, cf);
    hipLaunchKernelGGL(transpose_kernel, dim3(768), dim3(256), 0, stream,
                       kf, kfT);
    hipLaunchKernelGGL(attn_kernel, dim3(768), dim3(512), 0, stream,
                       kf, kfT, cf, part);
    hipLaunchKernelGGL(reduce_kernel, dim3(512), dim3(256), 0, stream,
                       (const float4*)part, (float4*)out);
}

// Round 6
// 190.462 us; speedup vs baseline: 1.0296x; 1.0296x over previous
//
#include <hip/hip_runtime.h>

// Problem constants (from setup_inputs)
#define V_    50000
#define D_    128
#define HOPS_ 3
#define B_    16
#define LC_   256
#define MC_   8
#define LK_   512
#define MK_   8

typedef __bf16  bf16x8  __attribute__((ext_vector_type(8)));
typedef unsigned short ushort8 __attribute__((ext_vector_type(8)));
typedef unsigned short ushort4v __attribute__((ext_vector_type(4)));
typedef float   floatx4 __attribute__((ext_vector_type(4)));

__device__ inline unsigned short f2bf(float f) {
    union { float f; unsigned u; } x; x.f = f;
    unsigned r = x.u + 0x7FFFu + ((x.u >> 16) & 1u);   // RNE
    return (unsigned short)(r >> 16);
}

__device__ inline floatx4 mfma_bf16(ushort8 a, ushort8 b, floatx4 c) {
    return __builtin_amdgcn_mfma_f32_16x16x32_bf16(
        __builtin_bit_cast(bf16x8, a), __builtin_bit_cast(bf16x8, b), c, 0, 0, 0);
}

// ---------------------------------------------------------------------------
// Kernel 1: embedding-bag gathers + in-block kfT transpose + d_out zeroing.
// Gather is at its compulsory-traffic floor (R3/R4 neutral) — structure kept.
// kf blocks transpose their own 32x128 tile through an 8.4 KB bf16 LDS tile
// (stride 132 ushorts: 8B-aligned rows, <=4-way conflicts) -> no separate
// transpose kernel. Occupancy stays 7 blocks/CU (VGPR-capped; LDS 8.4KB).
//   blocks [0,768):      kf tiles (hop,b,ktile of 32 rows) + kfT
//   blocks [768,1152):   cf tiles (hop,b,ltile of 32 rows)
//   blocks [1152,1664):  zero d_out (512 blocks x 256 thr x float4)
// ---------------------------------------------------------------------------
__global__ __launch_bounds__(256, 7) void gather_kernel(
    const int* __restrict__ conv_seqs, const int* __restrict__ kb_arr,
    const float* __restrict__ Ct, const float* __restrict__ Kt,
    unsigned short* __restrict__ kf, unsigned short* __restrict__ kfT,
    unsigned short* __restrict__ cf, float4* __restrict__ out4)
{
    __shared__ unsigned short tile[32][132];

    const int tid  = threadIdx.x;
    const int bx   = blockIdx.x;

    constexpr int KBLK = HOPS_ * B_ * (LK_ / 32);   // 768
    constexpr int CBLK = HOPS_ * B_ * (LC_ / 32);   // 384

    if (bx >= KBLK + CBLK) {                 // zero-out blocks
        out4[(size_t)(bx - (KBLK + CBLK)) * 256 + tid] =
            make_float4(0.f, 0.f, 0.f, 0.f);
        return;
    }

    const int r    = tid >> 3;               // row in tile (0..31)
    const int s    = tid & 7;                // position within 8-lane cluster
    const int lane = tid & 63;

    const int*   idxp;
    const float* table;
    unsigned short* dst;                     // row base (element 0)
    bool do_transpose;
    int g, row0;

    if (bx < KBLK) {
        int hop  = bx / (B_ * 16);
        int rem  = bx % (B_ * 16);
        int b    = rem >> 4;
        row0 = (rem & 15) * 32;
        g    = hop * B_ + b;
        idxp  = kb_arr + (size_t)(b * LK_ + row0 + r) * MK_;
        table = Kt + (size_t)hop * V_ * D_;
        dst   = kf + ((size_t)g * LK_ + row0 + r) * D_;
        do_transpose = true;
    } else {
        int id   = bx - KBLK;
        int hop  = id / (B_ * 8);
        int rem  = id % (B_ * 8);
        int b    = rem >> 3;
        row0 = (rem & 7) * 32;
        g    = hop * B_ + b;
        idxp  = conv_seqs + (size_t)(b * LC_ + row0 + r) * MC_;
        table = Ct + (size_t)hop * V_ * D_;
        dst   = cf + ((size_t)g * LC_ + row0 + r) * D_;
        do_transpose = false;
    }

    const int myidx = idxp[s];               // one idx per lane, coalesced
    int idxs[8];
    #pragma unroll
    for (int m = 0; m < 8; ++m)
        idxs[m] = __shfl(myidx, (lane & 56) + m);

    float4 acc[4];
    #pragma unroll
    for (int j = 0; j < 4; ++j) acc[j] = make_float4(0.f, 0.f, 0.f, 0.f);

    #pragma unroll
    for (int m = 0; m < 8; ++m) {
        const float* rowp = table + (size_t)idxs[m] * D_;
        #pragma unroll
        for (int j = 0; j < 4; ++j) {
            float4 v = *(const float4*)(rowp + j * 32 + s * 4);
            acc[j].x += v.x; acc[j].y += v.y; acc[j].z += v.z; acc[j].w += v.w;
        }
    }

    ushort4v o[4];
    #pragma unroll
    for (int j = 0; j < 4; ++j) {
        o[j][0] = f2bf(acc[j].x); o[j][1] = f2bf(acc[j].y);
        o[j][2] = f2bf(acc[j].z); o[j][3] = f2bf(acc[j].w);
        *(ushort4v*)(dst + j * 32 + s * 4) = o[j];   // 8B/lane, cluster-contig
    }

    if (do_transpose) {
        #pragma unroll
        for (int j = 0; j < 4; ++j)
            *(ushort4v*)&tile[r][j * 32 + s * 4] = o[j];
        __syncthreads();
        // thread t: d = t>>1, k-halves of 16; pairs give 64B contiguous
        const int d    = tid >> 1;
        const int half = tid & 1;
        unsigned short* tdst =
            kfT + ((size_t)g * D_ + d) * LK_ + row0 + half * 16;
        ushort8 a, b;
        #pragma unroll
        for (int i = 0; i < 8; ++i) a[i] = tile[half * 16 + i][d];
        #pragma unroll
        for (int i = 0; i < 8; ++i) b[i] = tile[half * 16 + 8 + i][d];
        *(ushort8*)(tdst)     = a;
        *(ushort8*)(tdst + 8) = b;
    }
}

// ---------------------------------------------------------------------------
// Kernel 2: attention, hop-parallel, XCD-swizzled. One block per
// (hop, b, 16-query tile): 768 blocks x 512 thr (3 blocks/CU).
//   Phase A: att[16][512] = cf_tile @ kf^T (raw fp32 scores -> att_s)
//   softmax: per-wave shuffle butterfly, 2 rows/wave; e stored as bf16 in
//            p_s (A-fragment-ready) — Phase B has zero convert work
//   Phase B: p_s @ kfT fragments; 1/sum folded in; hop-sum via atomicAdd
//            (R4 measured: atomics are free here). 2 barriers total.
// ---------------------------------------------------------------------------
__global__ __launch_bounds__(512) void attn_kernel(
    const unsigned short* __restrict__ kf, const unsigned short* __restrict__ kfT,
    const unsigned short* __restrict__ cf, float* __restrict__ out)
{
    constexpr int AS = 516;                  // fp32 score stride
    constexpr int PS = 520;                  // bf16 p stride (1040B, 16B-aligned)
    __shared__ float att_s[16][AS];          // 33.0 KB
    __shared__ unsigned short p_s[16][PS];   // 16.6 KB
    __shared__ float rowinv_s[16];

    const int tid  = threadIdx.x;
    const int wave = tid >> 6;               // 0..7
    const int lane = tid & 63;
    const int quad = lane >> 4;              // 0..3
    const int l16  = lane & 15;

    // XCD-swizzle decode: all 16 l-tiles of a (hop,b) share bx%8
    const int gl  = blockIdx.x & 7;
    const int s_  = blockIdx.x >> 3;         // 0..95
    const int lt  = s_ / 6;                  // 0..15
    const int gh  = s_ % 6;                  // 0..5
    const int g   = gh * 8 + gl;             // 0..47 = hop*16+b
    const int b   = g & 15;
    const int l0  = lt * 16;

    const unsigned short* cf_h  = cf  + (((size_t)g) * 256 + l0) * 128;
    const unsigned short* kf_h  = kf  + ((size_t)g) * 512 * 128;
    const unsigned short* kfT_h = kfT + ((size_t)g) * 128 * 512;

    // A-fragments (cf rows), reused across all 32 n-tiles
    ushort8 afrag[4];
    #pragma unroll
    for (int ks = 0; ks < 4; ++ks)
        afrag[ks] = *(const ushort8*)(cf_h + l16 * 128 + ks * 32 + quad * 8);

    // -------- Phase A: att = cf @ kf^T --------
    #pragma unroll
    for (int t = 0; t < 4; ++t) {
        const int nt = wave * 4 + t;         // 8 waves x 4 = 32 n-tiles (512 k)
        floatx4 acc = {0.f, 0.f, 0.f, 0.f};
        #pragma unroll
        for (int ks = 0; ks < 4; ++ks) {
            ushort8 bfrag = *(const ushort8*)(kf_h + (nt * 16 + l16) * 128 + ks * 32 + quad * 8);
            acc = mfma_bf16(afrag[ks], bfrag, acc);
        }
        #pragma unroll
        for (int rr = 0; rr < 4; ++rr)
            att_s[quad * 4 + rr][nt * 16 + l16] = acc[rr];
    }
    __syncthreads();

    // -------- softmax: wave handles rows 2*wave, 2*wave+1; emit bf16 p_s ----
    #pragma unroll
    for (int rr = 0; rr < 2; ++rr) {
        const int row = wave * 2 + rr;
        float v[8];
        float mx = -1e30f;
        #pragma unroll
        for (int j = 0; j < 8; ++j) {
            v[j] = att_s[row][lane + j * 64];
            mx = fmaxf(mx, v[j]);
        }
        #pragma unroll
        for (int off = 32; off; off >>= 1) mx = fmaxf(mx, __shfl_xor(mx, off));
        float sum = 0.f;
        #pragma unroll
        for (int j = 0; j < 8; ++j) {
            float e = __expf(v[j] - mx);
            p_s[row][lane + j * 64] = f2bf(e);   // 2 lanes/bank-word: free
            sum += e;
        }
        #pragma unroll
        for (int off = 32; off; off >>= 1) sum += __shfl_xor(sum, off);
        if (lane == 0) rowinv_s[row] = 1.0f / sum;
    }
    __syncthreads();

    // -------- Phase B: out_tile = p @ kf  (wave owns d-tile = wave) --------
    floatx4 pacc = {0.f, 0.f, 0.f, 0.f};
    #pragma unroll
    for (int ks = 0; ks < 16; ++ks) {
        ushort8 pa    = *(const ushort8*)&p_s[l16][ks * 32 + quad * 8];
        ushort8 bfrag = *(const ushort8*)(kfT_h + (size_t)(wave * 16 + l16) * 512 + ks * 32 + quad * 8);
        pacc = mfma_bf16(pa, bfrag, pacc);
    }

    // out layout: [Lc, B, D]; hop-sum via atomics (measured free in R4)
    const int d = wave * 16 + l16;
    #pragma unroll
    for (int rr = 0; rr < 4; ++rr)
        atomicAdd(&out[(((size_t)(l0 + quad * 4 + rr)) * 16 + b) * 128 + d],
                  pacc[rr] * rowinv_s[quad * 4 + rr]);
}

extern "C" void kernel_launch(void* const* d_in, const int* in_sizes, int n_in,
                              void* d_out, int out_size, void* d_ws, size_t ws_size,
                              hipStream_t stream) {
    (void)in_sizes; (void)n_in; (void)out_size; (void)ws_size;
    const int*   conv_seqs = (const int*)d_in[0];
    const int*   kb_arr    = (const int*)d_in[1];
    const float* C         = (const float*)d_in[2];
    const float* K         = (const float*)d_in[3];

    // ws layout (bf16): kf [3][16][512][128], kfT [3][16][128][512], cf [3][16][256][128]
    unsigned short* kf  = (unsigned short*)d_ws;
    unsigned short* kfT = kf  + (size_t)HOPS_ * B_ * LK_ * D_;
    unsigned short* cf  = kfT + (size_t)HOPS_ * B_ * LK_ * D_;
    float* out = (float*)d_out;

    // 768 kf + 384 cf + 512 zero-out blocks
    hipLaunchKernelGGL(gather_kernel, dim3(1664), dim3(256), 0, stream,
                       conv_seqs, kb_arr, C, K, kf, kfT, cf, (float4*)out);
    hipLaunchKernelGGL(attn_kernel, dim3(768), dim3(512), 0, stream,
                       kf, kfT, cf, out);
}

// Round 7
// 189.150 us; speedup vs baseline: 1.0367x; 1.0069x over previous
//
#include <hip/hip_runtime.h>

// Problem constants (from setup_inputs)
#define V_    50000
#define D_    128
#define HOPS_ 3
#define B_    16
#define LC_   256
#define MC_   8
#define LK_   512
#define MK_   8

typedef __bf16  bf16x8  __attribute__((ext_vector_type(8)));
typedef unsigned short ushort8 __attribute__((ext_vector_type(8)));
typedef unsigned short ushort4v __attribute__((ext_vector_type(4)));
typedef float   floatx4 __attribute__((ext_vector_type(4)));

__device__ inline unsigned short f2bf(float f) {
    union { float f; unsigned u; } x; x.f = f;
    unsigned r = x.u + 0x7FFFu + ((x.u >> 16) & 1u);   // RNE
    return (unsigned short)(r >> 16);
}

__device__ inline floatx4 mfma_bf16(ushort8 a, ushort8 b, floatx4 c) {
    return __builtin_amdgcn_mfma_f32_16x16x32_bf16(
        __builtin_bit_cast(bf16x8, a), __builtin_bit_cast(bf16x8, b), c, 0, 0, 0);
}

// ---------------------------------------------------------------------------
// Kernel 1: K-table embedding-bag gather + in-block kfT transpose + d_out
// zeroing. cf moved into attn (sole consumer). 16-row tiles: a 16-lane
// cluster covers one full 512B table row contiguously (2 b128/lane/token ->
// all 16 loads in flight within VGPR budget).
//   blocks [0,1536):     kf tiles (hop,b,ktile of 16 rows) + kfT
//   blocks [1536,2048):  zero d_out (512 blocks x 256 thr x float4)
// ---------------------------------------------------------------------------
__global__ __launch_bounds__(256, 6) void gather_kernel(
    const int* __restrict__ kb_arr, const float* __restrict__ Kt,
    unsigned short* __restrict__ kf, unsigned short* __restrict__ kfT,
    float4* __restrict__ out4)
{
    __shared__ unsigned short tile[16][136];     // 4.4 KB, pad for transpose

    const int tid  = threadIdx.x;
    const int bx   = blockIdx.x;

    constexpr int KBLK = HOPS_ * B_ * (LK_ / 16);   // 1536

    if (bx >= KBLK) {                        // zero-out blocks
        out4[(size_t)(bx - KBLK) * 256 + tid] = make_float4(0.f, 0.f, 0.f, 0.f);
        return;
    }

    const int r    = tid >> 4;               // row in tile (0..15)
    const int s    = tid & 15;               // position in 16-lane cluster
    const int lane = tid & 63;

    const int hop  = bx / (B_ * 32);
    const int rem  = bx % (B_ * 32);
    const int b    = rem >> 5;
    const int row0 = (rem & 31) * 16;
    const int g    = hop * B_ + b;

    const int* idxp = kb_arr + (size_t)(b * LK_ + row0 + r) * MK_;
    const float* table = Kt + (size_t)hop * V_ * D_;
    unsigned short* dst = kf + ((size_t)g * LK_ + row0 + r) * D_;

    const int myidx = idxp[s & 7];           // 8 idx per row, loaded twice
    int idxs[8];
    #pragma unroll
    for (int m = 0; m < 8; ++m)
        idxs[m] = __shfl(myidx, (lane & 48) + m);    // 16-lane cluster base

    float4 a0 = make_float4(0.f, 0.f, 0.f, 0.f);
    float4 a1 = make_float4(0.f, 0.f, 0.f, 0.f);

    #pragma unroll
    for (int m = 0; m < 8; ++m) {
        const float4* rowp = (const float4*)(table + (size_t)idxs[m] * D_);
        float4 v0 = rowp[s * 2];
        float4 v1 = rowp[s * 2 + 1];
        a0.x += v0.x; a0.y += v0.y; a0.z += v0.z; a0.w += v0.w;
        a1.x += v1.x; a1.y += v1.y; a1.z += v1.z; a1.w += v1.w;
    }

    ushort8 o;
    o[0] = f2bf(a0.x); o[1] = f2bf(a0.y); o[2] = f2bf(a0.z); o[3] = f2bf(a0.w);
    o[4] = f2bf(a1.x); o[5] = f2bf(a1.y); o[6] = f2bf(a1.z); o[7] = f2bf(a1.w);
    *(ushort8*)(dst + s * 8) = o;            // cluster writes 256B contiguous

    // transpose through LDS -> kfT
    *(ushort8*)&tile[r][s * 8] = o;
    __syncthreads();
    const int d    = tid >> 1;               // 0..127
    const int half = tid & 1;                // k-halves of 8
    unsigned short* tdst = kfT + ((size_t)g * D_ + d) * LK_ + row0 + half * 8;
    ushort8 t8;
    #pragma unroll
    for (int i = 0; i < 8; ++i) t8[i] = tile[half * 8 + i][d];
    *(ushort8*)(tdst) = t8;                  // thread-pairs: 32B contiguous
}

// ---------------------------------------------------------------------------
// Kernel 2: attention, hop-parallel, XCD-swizzled, with in-kernel cf gather.
// One block per (hop, b, 16-query tile): 768 blocks x 512 thr (3 blocks/CU).
//   cf gather: 16 bags x 8 tokens of C-rows summed by 32 thr/bag -> bf16 LDS
//              (overlaid on p_s: cf dead before softmax writes p_s)
//   Phase A: att[16][512] = cf_tile @ kf^T  (fp32 scores -> att_s)
//   softmax: per-wave shuffle butterfly, 2 rows/wave; emits bf16 p_s
//   Phase B: p_s @ kfT fragments; 1/sum folded; hop-sum via atomicAdd.
// LDS 49.7 KB -> 3 blocks/CU.
// ---------------------------------------------------------------------------
__global__ __launch_bounds__(512) void attn_kernel(
    const int* __restrict__ conv_seqs, const float* __restrict__ Ct,
    const unsigned short* __restrict__ kf, const unsigned short* __restrict__ kfT,
    float* __restrict__ out)
{
    constexpr int AS = 516;                  // fp32 score stride
    constexpr int PS = 520;                  // bf16 p stride
    __shared__ float att_s[16][AS];          // 33.0 KB
    __shared__ unsigned short p_s[16][PS];   // 16.6 KB (also hosts cf tile)
    __shared__ float rowinv_s[16];

    // cf tile overlay on p_s: element (bag,d) at p_s flat [bag*132 + d]
    unsigned short* cf_s = &p_s[0][0];

    const int tid  = threadIdx.x;
    const int wave = tid >> 6;               // 0..7
    const int lane = tid & 63;
    const int quad = lane >> 4;              // 0..3
    const int l16  = lane & 15;

    // XCD-swizzle decode: all 16 l-tiles of a (hop,b) share bx%8
    const int gl  = blockIdx.x & 7;
    const int s_  = blockIdx.x >> 3;         // 0..95
    const int lt  = s_ / 6;                  // 0..15
    const int gh  = s_ % 6;                  // 0..5
    const int g   = gh * 8 + gl;             // 0..47 = hop*16+b
    const int hop = g >> 4;
    const int b   = g & 15;
    const int l0  = lt * 16;

    const unsigned short* kf_h  = kf  + ((size_t)g) * 512 * 128;
    const unsigned short* kfT_h = kfT + ((size_t)g) * 128 * 512;

    // -------- cf gather: bag = tid>>5 (16 bags), 32 thr/bag, 4 d-elems -----
    {
        const int bag = tid >> 5;
        const int sl  = tid & 31;
        const int d0  = sl * 4;
        const int* idxp = conv_seqs + (size_t)(b * LC_ + l0 + bag) * MC_;
        const float* table = Ct + (size_t)hop * V_ * D_;
        float4 acc = make_float4(0.f, 0.f, 0.f, 0.f);
        #pragma unroll
        for (int m = 0; m < 8; ++m) {
            const float4 v = *(const float4*)(table + (size_t)idxp[m] * D_ + d0);
            acc.x += v.x; acc.y += v.y; acc.z += v.z; acc.w += v.w;
        }
        ushort4v oc;
        oc[0] = f2bf(acc.x); oc[1] = f2bf(acc.y);
        oc[2] = f2bf(acc.z); oc[3] = f2bf(acc.w);
        *(ushort4v*)&cf_s[bag * 132 + d0] = oc;
    }
    __syncthreads();

    // A-fragments (cf rows), reused across all 32 n-tiles
    ushort8 afrag[4];
    #pragma unroll
    for (int ks = 0; ks < 4; ++ks)
        afrag[ks] = *(const ushort8*)&cf_s[l16 * 132 + ks * 32 + quad * 8];

    // -------- Phase A: att = cf @ kf^T --------
    #pragma unroll
    for (int t = 0; t < 4; ++t) {
        const int nt = wave * 4 + t;         // 8 waves x 4 = 32 n-tiles (512 k)
        floatx4 acc = {0.f, 0.f, 0.f, 0.f};
        #pragma unroll
        for (int ks = 0; ks < 4; ++ks) {
            ushort8 bfrag = *(const ushort8*)(kf_h + (nt * 16 + l16) * 128 + ks * 32 + quad * 8);
            acc = mfma_bf16(afrag[ks], bfrag, acc);
        }
        #pragma unroll
        for (int rr = 0; rr < 4; ++rr)
            att_s[quad * 4 + rr][nt * 16 + l16] = acc[rr];
    }
    __syncthreads();                         // also fences afrag reads of cf_s

    // -------- softmax: wave handles rows 2*wave, 2*wave+1; emit bf16 p_s ----
    #pragma unroll
    for (int rr = 0; rr < 2; ++rr) {
        const int row = wave * 2 + rr;
        float v[8];
        float mx = -1e30f;
        #pragma unroll
        for (int j = 0; j < 8; ++j) {
            v[j] = att_s[row][lane + j * 64];
            mx = fmaxf(mx, v[j]);
        }
        #pragma unroll
        for (int off = 32; off; off >>= 1) mx = fmaxf(mx, __shfl_xor(mx, off));
        float sum = 0.f;
        #pragma unroll
        for (int j = 0; j < 8; ++j) {
            float e = __expf(v[j] - mx);
            p_s[row][lane + j * 64] = f2bf(e);
            sum += e;
        }
        #pragma unroll
        for (int off = 32; off; off >>= 1) sum += __shfl_xor(sum, off);
        if (lane == 0) rowinv_s[row] = 1.0f / sum;
    }
    __syncthreads();

    // -------- Phase B: out_tile = p @ kf  (wave owns d-tile = wave) --------
    floatx4 pacc = {0.f, 0.f, 0.f, 0.f};
    #pragma unroll
    for (int ks = 0; ks < 16; ++ks) {
        ushort8 pa    = *(const ushort8*)&p_s[l16][ks * 32 + quad * 8];
        ushort8 bfrag = *(const ushort8*)(kfT_h + (size_t)(wave * 16 + l16) * 512 + ks * 32 + quad * 8);
        pacc = mfma_bf16(pa, bfrag, pacc);
    }

    // out layout: [Lc, B, D]; hop-sum via atomics (measured free in R4)
    const int d = wave * 16 + l16;
    #pragma unroll
    for (int rr = 0; rr < 4; ++rr)
        atomicAdd(&out[(((size_t)(l0 + quad * 4 + rr)) * 16 + b) * 128 + d],
                  pacc[rr] * rowinv_s[quad * 4 + rr]);
}

extern "C" void kernel_launch(void* const* d_in, const int* in_sizes, int n_in,
                              void* d_out, int out_size, void* d_ws, size_t ws_size,
                              hipStream_t stream) {
    (void)in_sizes; (void)n_in; (void)out_size; (void)ws_size;
    const int*   conv_seqs = (const int*)d_in[0];
    const int*   kb_arr    = (const int*)d_in[1];
    const float* C         = (const float*)d_in[2];
    const float* K         = (const float*)d_in[3];

    // ws layout (bf16): kf [3][16][512][128], kfT [3][16][128][512]
    unsigned short* kf  = (unsigned short*)d_ws;
    unsigned short* kfT = kf + (size_t)HOPS_ * B_ * LK_ * D_;
    float* out = (float*)d_out;

    // 1536 kf blocks + 512 zero-out blocks
    hipLaunchKernelGGL(gather_kernel, dim3(2048), dim3(256), 0, stream,
                       kb_arr, K, kf, kfT, (float4*)out);
    hipLaunchKernelGGL(attn_kernel, dim3(768), dim3(512), 0, stream,
                       conv_seqs, C, kf, kfT, out);
}